// Round 3
// baseline (7267.684 us; speedup 1.0000x reference)
//
#include <hip/hip_runtime.h>

typedef unsigned short u16;
typedef unsigned int u32;
typedef __bf16 bf16x8 __attribute__((ext_vector_type(8)));
typedef float f32x4 __attribute__((ext_vector_type(4)));

#define B_ 256
#define T_ 128
#define E_ 300
#define EP 320
#define H_ 2048
#define G_ 8192

// ws layout (bytes)
#define OFF_XBF   0UL
#define OFF_WIH   20971520UL
#define OFF_WHH   26214400UL
#define OFF_BIAS  59768832UL
#define OFF_BAR   59801600UL
#define OFF_HBUF  59802112UL   // 127 fresh h buffers x 1 MB = 133,169,152 B

__device__ __forceinline__ u16 f2bf(float f) {
  u32 u = __builtin_bit_cast(u32, f);
  return (u16)((u + 0x7FFFu + ((u >> 16) & 1u)) >> 16);
}
__device__ __forceinline__ float sigm_f(float x) {
  return __builtin_amdgcn_rcpf(1.0f + __expf(-x));
}
__device__ __forceinline__ float tanh_f(float x) {
  return 1.0f - 2.0f * __builtin_amdgcn_rcpf(1.0f + __expf(2.0f * x));
}

// ---------------- prep: pack/convert to bf16, zero barrier flags ----------------
__global__ void prep_kernel(const float* __restrict__ x, const float* __restrict__ Wih,
                            const float* __restrict__ Whh, const float* __restrict__ bih,
                            const float* __restrict__ bhh, u16* __restrict__ xbf,
                            u16* __restrict__ wihb, u16* __restrict__ whhb,
                            float* __restrict__ biasc, u32* __restrict__ bar) {
  const long NX = (long)T_ * B_ * EP;
  const long NWIH = (long)G_ * EP;
  const long NWHH = (long)G_ * H_;
  const long NBS = G_;
  const long NBAR = T_;
  const long total = NX + NWIH + NWHH + NBS + NBAR;
  for (long q = (long)blockIdx.x * blockDim.x + threadIdx.x; q < total;
       q += (long)gridDim.x * blockDim.x) {
    long r = q;
    if (r < NX) {
      int t = (int)(r / (B_ * EP));
      int rem = (int)(r % (B_ * EP));
      int b = rem / EP, e = rem % EP;
      float v = (e < E_) ? x[((long)b * T_ + t) * E_ + e] : 0.0f;
      xbf[r] = f2bf(v);
    } else if ((r -= NX) < NWIH) {
      int n = (int)(r / EP), e = (int)(r % EP);
      wihb[r] = f2bf((e < E_) ? Wih[(long)n * E_ + e] : 0.0f);
    } else if ((r -= NWIH) < NWHH) {
      whhb[r] = f2bf(Whh[r]);   // [8192,2048] row-major == B^T layout
    } else if ((r -= NWHH) < NBS) {
      biasc[r] = bih[r] + bhh[r];
    } else {
      r -= NBS;
      bar[r] = 0;
    }
  }
}

// ---------------- main persistent LSTM kernel ----------------
// 256 blocks x 256 thr, 1 block/CU. Block tile: 64 batch rows x (32 j x 4 gates).
// Wave grid 2x2: wave tile 32m x (16j x 4 gates). NO LDS, NO K-loop barriers:
// fragments load straight to VGPRs (compiler emits fine-grained vmcnt), waves
// free-run; A/B duplication across the wave pairs is L1-absorbed.
// h coherence: per-step FRESH 1MB buffer (never cached => plain loads are
// coherent); producers store write-through (sc0 sc1); relaxed-flag barrier.
__global__ void __launch_bounds__(256, 1)
lstm_kernel(const u16* __restrict__ xbf, const u16* __restrict__ wihb,
            const u16* __restrict__ whhb, const float* __restrict__ biasc,
            u16* __restrict__ hbufs, u32* __restrict__ bar, float* __restrict__ out) {
  const int tid = threadIdx.x;
  const int l = tid & 63;
  const int w = tid >> 6;
  const int wr = w >> 1, wj = w & 1;
  const int bid = blockIdx.x;
  const int b0 = (bid >> 6) << 6;           // 4 gb-siblings of a gn share bid%8 (XCD)
  const int j0 = (bid & 63) << 5;
  const int arow = (wr << 5) + (l & 15);    // A m-row within block tile
  const int koff = (l >> 4) << 3;           // k-offset within 32-chunk
  const int jc = j0 + (wj << 4) + (l & 15); // output column / B row base

  const float bi = biasc[jc];
  const float bff = biasc[2048 + jc];
  const float bg = biasc[4096 + jc];
  const float bo = biasc[6144 + jc];

  float cst[2][4];
#pragma unroll
  for (int mi = 0; mi < 2; ++mi)
#pragma unroll
    for (int r = 0; r < 4; ++r) cst[mi][r] = 0.0f;

  __shared__ u32 fv_sh;

  f32x4 acc[2][4];

  // register-fragment GEMM phase: acc += A[64 x K] * B[(4g x 16j) x K]^T
  auto gemm_phase = [&](const u16* asrc, int astr, const u16* bsrc, int bstr,
                        int kiters) {
    bf16x8 af[2][2][2];   // [buf][mi][k2]
    bf16x8 bfr[2][2][4];  // [buf][k2][g]
    auto ld = [&](int buf, int kk) {
#pragma unroll
      for (int mi = 0; mi < 2; ++mi)
#pragma unroll
        for (int k2 = 0; k2 < 2; ++k2)
          af[buf][mi][k2] = *(const bf16x8*)(asrc +
              (size_t)(arow + (mi << 4)) * astr + kk + (k2 << 5) + koff);
#pragma unroll
      for (int k2 = 0; k2 < 2; ++k2)
#pragma unroll
        for (int g = 0; g < 4; ++g)
          bfr[buf][k2][g] = *(const bf16x8*)(bsrc +
              (size_t)((g << 11) + jc) * bstr + kk + (k2 << 5) + koff);
    };
    ld(0, 0);
#pragma unroll 2
    for (int k = 0; k < kiters; ++k) {
      int cur = k & 1;
      if (k + 1 < kiters) ld(cur ^ 1, (k + 1) << 6);   // depth-1 prefetch
#pragma unroll
      for (int k2 = 0; k2 < 2; ++k2)
#pragma unroll
        for (int g = 0; g < 4; ++g) {
          acc[0][g] = __builtin_amdgcn_mfma_f32_16x16x32_bf16(
              af[cur][0][k2], bfr[cur][k2][g], acc[0][g], 0, 0, 0);
          acc[1][g] = __builtin_amdgcn_mfma_f32_16x16x32_bf16(
              af[cur][1][k2], bfr[cur][k2][g], acc[1][g], 0, 0, 0);
        }
    }
  };

#pragma unroll 1
  for (int t = 0; t < T_; ++t) {
#pragma unroll
    for (int mi = 0; mi < 2; ++mi)
#pragma unroll
      for (int g = 0; g < 4; ++g) acc[mi][g] = (f32x4){0.f, 0.f, 0.f, 0.f};

    // ---- x phase (no h dependency): runs before the flag wait, hides skew
    const u16* xsrc = xbf + (size_t)t * (B_ * EP) + (size_t)b0 * EP;
    gemm_phase(xsrc, EP, wihb, EP, 5);

    // ---- h phase (skipped at t=0: h==0)
    if (t > 0) {
      if (tid == 0) {
        u32 f;
        while ((f = __hip_atomic_load(&bar[t - 1], __ATOMIC_RELAXED,
                                      __HIP_MEMORY_SCOPE_AGENT)) < 256u)
          __builtin_amdgcn_s_sleep(2);
        fv_sh = f;
      }
      __syncthreads();
      // data-dependence shield: h address depends on observed flag (>>31 == 0)
      const u16* hsrc = hbufs + (size_t)(t - 1) * (B_ * H_) +
                        (size_t)b0 * H_ + (fv_sh >> 31);
      gemm_phase(hsrc, H_, whhb, H_, 32);
    }

    // ---- lane-local LSTM pointwise; c stays in registers across steps
    u16* hnxt = hbufs + (size_t)t * (B_ * H_);
#pragma unroll
    for (int mi = 0; mi < 2; ++mi) {
#pragma unroll
      for (int r = 0; r < 4; ++r) {
        float ig = sigm_f(acc[mi][0][r] + bi);
        float fg = sigm_f(acc[mi][1][r] + bff);
        float gg = tanh_f(acc[mi][2][r] + bg);
        float og = sigm_f(acc[mi][3][r] + bo);
        float c = fg * cst[mi][r] + ig * gg;
        cst[mi][r] = c;
        float h = og * tanh_f(c);
        int row = b0 + (wr << 5) + (mi << 4) + ((l >> 4) << 2) + r;
        if (t < T_ - 1) {
          u16 hv = f2bf(h);
          u16* hp = hnxt + (size_t)row * H_ + jc;
          asm volatile("global_store_short %0, %1, off sc0 sc1"
                       :: "v"(hp), "v"((u32)hv) : "memory");
        } else {
          out[(size_t)row * H_ + jc] = h;
        }
      }
    }

    if (t < T_ - 1) {
      __builtin_amdgcn_s_waitcnt(0);      // h stores reached coherent point
      __syncthreads();                    // all 4 waves drained
      if (tid == 0)
        __hip_atomic_fetch_add(&bar[t], 1u, __ATOMIC_RELAXED,
                               __HIP_MEMORY_SCOPE_AGENT);
    }
  }
}

extern "C" void kernel_launch(void* const* d_in, const int* in_sizes, int n_in,
                              void* d_out, int out_size, void* d_ws, size_t ws_size,
                              hipStream_t stream) {
  const float* x = (const float*)d_in[0];
  const float* Wih = (const float*)d_in[1];
  const float* Whh = (const float*)d_in[2];
  const float* bih = (const float*)d_in[3];
  const float* bhh = (const float*)d_in[4];
  char* ws = (char*)d_ws;
  u16* xbf = (u16*)(ws + OFF_XBF);
  u16* wihb = (u16*)(ws + OFF_WIH);
  u16* whhb = (u16*)(ws + OFF_WHH);
  float* biasc = (float*)(ws + OFF_BIAS);
  u32* bar = (u32*)(ws + OFF_BAR);
  u16* hbufs = (u16*)(ws + OFF_HBUF);
  float* out = (float*)d_out;

  hipLaunchKernelGGL(prep_kernel, dim3(2048), dim3(256), 0, stream,
                     x, Wih, Whh, bih, bhh, xbf, wihb, whhb, biasc, bar);

  void* args[] = {(void*)&xbf, (void*)&wihb, (void*)&whhb,
                  (void*)&biasc, (void*)&hbufs, (void*)&bar, (void*)&out};
  hipLaunchCooperativeKernel((void*)lstm_kernel, dim3(256), dim3(256), args, 0, stream);
}